// Round 11
// baseline (81.946 us; speedup 1.0000x reference)
//
#include <hip/hip_runtime.h>

#define NB 4
#define SS 2048
#define DM 512
#define DD 64
#define NR (NB*SS)
#define KLEN 256

typedef __attribute__((ext_vector_type(8))) short bf16x8;
typedef __attribute__((ext_vector_type(4))) float f32x4;

static __device__ __forceinline__ unsigned short f2b(float f) {
  union { float f; unsigned u; } x; x.f = f;
  unsigned r = x.u + 0x7FFFu + ((x.u >> 16) & 1u);
  return (unsigned short)(r >> 16);
}
static __device__ __forceinline__ bf16x8 ld8(const unsigned short* p) {
  union { uint4 u; bf16x8 v; } x; x.u = *(const uint4*)p; return x.v;
}
// async global->LDS, 16B per lane; LDS dest = wave-uniform base + lane*16
static __device__ __forceinline__ void glds16(const void* g, void* l) {
  auto gp = (const __attribute__((address_space(1))) unsigned*)((__UINTPTR_TYPE__)g);
  auto lp = (__attribute__((address_space(3))) unsigned*)((__UINTPTR_TYPE__)l);
  __builtin_amdgcn_global_load_lds(gp, lp, 16, 0, 0);
}

// ------- mask dtype detection: stride-64 sampled scan -------
__global__ __launch_bounds__(256) void detect_mask(const unsigned* __restrict__ mw,
                                                   int nwords, int* __restrict__ part) {
  const int gid = blockIdx.x * 256 + threadIdx.x;
  const int nthr = gridDim.x * 256;
  int vi = 0, vf = 0, vu = 0;
  for (long i = (long)gid * 64; i < nwords; i += (long)nthr * 64) {
    unsigned w = mw[i];
    vi |= (w > 1u);
    vf |= ((w != 0u) & (w != 0x3F800000u));
    vu |= ((w & 0xFEFEFEFEu) != 0u);
  }
  __shared__ int sh[3];
  if (threadIdx.x < 3) sh[threadIdx.x] = 0;
  __syncthreads();
  int lane = threadIdx.x & 63;
  unsigned long long b;
  b = __ballot(vi); if (lane == 0 && b) sh[0] = 1;   // benign same-value races
  b = __ballot(vf); if (lane == 0 && b) sh[1] = 1;
  b = __ballot(vu); if (lane == 0 && b) sh[2] = 1;
  __syncthreads();
  if (threadIdx.x < 3) part[blockIdx.x * 4 + threadIdx.x] = sh[threadIdx.x];
}

__global__ __launch_bounds__(256) void reduce_flags(const int* __restrict__ part,
                                                    int nblk, int* __restrict__ viol) {
  int j = threadIdx.x;
  int a0 = 0, a1 = 0, a2 = 0;
  for (int i = j; i < nblk; i += 256) {
    a0 |= part[i * 4]; a1 |= part[i * 4 + 1]; a2 |= part[i * 4 + 2];
  }
  __shared__ int sh[3];
  if (j < 3) sh[j] = 0;
  __syncthreads();
  unsigned long long b0 = __ballot(a0), b1 = __ballot(a1), b2 = __ballot(a2);
  if ((j & 63) == 0) {
    if (b0) sh[0] = 1;
    if (b1) sh[1] = 1;
    if (b2) sh[2] = 1;
  }
  __syncthreads();
  if (j < 3) viol[j] = sh[j];
}

// ------- Wq/Wk/Wv transpose: Wt[p][n=64][k=512] bf16 <- W[k][n] fp32 -------
__global__ __launch_bounds__(256) void transpose_w(
    const float* __restrict__ Wq, const float* __restrict__ Wk, const float* __restrict__ Wv,
    unsigned short* __restrict__ Wt) {
  const int p = blockIdx.y;
  const float* W = (p == 0) ? Wq : ((p == 1) ? Wk : Wv);
  const int k0 = blockIdx.x * 64;
  const int t = threadIdx.x;
  const int n0 = (t & 15) * 4;
  #pragma unroll
  for (int p2 = 0; p2 < 4; ++p2) {
    int k = k0 + (t >> 4) + 16 * p2;
    float4 w = *(const float4*)(W + (size_t)k * DD + n0);
    Wt[(size_t)(p * DD + n0 + 0) * DM + k] = f2b(w.x);
    Wt[(size_t)(p * DD + n0 + 1) * DM + k] = f2b(w.y);
    Wt[(size_t)(p * DD + n0 + 2) * DM + k] = f2b(w.z);
    Wt[(size_t)(p * DD + n0 + 3) * DM + k] = f2b(w.w);
  }
}

// ------- Wfc transpose: WfcT[n=512][k=64] bf16 <- Wfc[64][512] fp32 -------
__global__ __launch_bounds__(256) void transpose_wfc(
    const float* __restrict__ Wfc, unsigned short* __restrict__ WfcT) {
  const int n0 = blockIdx.x * 64;
  const int t = threadIdx.x;
  __shared__ unsigned short wt[64][68];   // [k][n]
  {
    int k = t >> 2, j = (t & 3) * 16;
    #pragma unroll
    for (int u = 0; u < 4; ++u) {
      float4 w = *(const float4*)(Wfc + (size_t)k * DM + n0 + j + 4 * u);
      wt[k][j + 4 * u + 0] = f2b(w.x);
      wt[k][j + 4 * u + 1] = f2b(w.y);
      wt[k][j + 4 * u + 2] = f2b(w.z);
      wt[k][j + 4 * u + 3] = f2b(w.w);
    }
  }
  __syncthreads();
  {
    int n = t >> 2, kq = (t & 3) * 16;
    unsigned short tmp[16];
    #pragma unroll
    for (int u = 0; u < 16; ++u) tmp[u] = wt[kq + u][n];
    *(uint4*)(WfcT + (size_t)(n0 + n) * DD + kq) = *(uint4*)&tmp[0];
    *(uint4*)(WfcT + (size_t)(n0 + n) * DD + kq + 8) = *(uint4*)&tmp[8];
  }
}

// ------- projections via MFMA; V output written TRANSPOSED (vpT[b][dv][key]) -------
__global__ __launch_bounds__(256, 4) void proj_mfma(
    const float* __restrict__ q, const float* __restrict__ k, const float* __restrict__ v,
    const unsigned short* __restrict__ Wt,
    const float* __restrict__ bq, const float* __restrict__ bk, const float* __restrict__ bv,
    unsigned short* __restrict__ qp, unsigned short* __restrict__ kp,
    unsigned short* __restrict__ vpT) {
  const int p = blockIdx.y;
  const float* X = (p == 0) ? q : ((p == 1) ? k : v);
  const float* bias = (p == 0) ? bq : ((p == 1) ? bk : bv);
  unsigned short* out = (p == 0) ? qp : kp;   // p==2 goes through vpT path
  const int row0 = blockIdx.x * 64;
  const int tid = threadIdx.x;
  const int wq = tid >> 6, lane = tid & 63, g = lane >> 4, c = lane & 15;
  __shared__ unsigned short x_s[64][72];
  f32x4 acc[4];
  #pragma unroll
  for (int s = 0; s < 4; ++s) acc[s] = (f32x4){0.f, 0.f, 0.f, 0.f};
  const unsigned short* wbase = Wt + (size_t)p * DD * DM;

  for (int k0 = 0; k0 < DM; k0 += 64) {
    __syncthreads();
    #pragma unroll
    for (int pp = 0; pp < 4; ++pp) {
      int f = tid + 256 * pp;
      int r = f >> 4, c4 = (f & 15) << 2;
      float4 xv = *(const float4*)(X + (size_t)(row0 + r) * DM + k0 + c4);
      uint2 u;
      u.x = (unsigned)f2b(xv.x) | ((unsigned)f2b(xv.y) << 16);
      u.y = (unsigned)f2b(xv.z) | ((unsigned)f2b(xv.w) << 16);
      *(uint2*)&x_s[r][c4] = u;
    }
    __syncthreads();
    const unsigned short* xrow = &x_s[wq * 16 + c][0];
    bf16x8 a0 = ld8(xrow + 8 * g);
    bf16x8 a1 = ld8(xrow + 32 + 8 * g);
    #pragma unroll
    for (int s = 0; s < 4; ++s) {
      const unsigned short* wrow = wbase + (size_t)(16 * s + c) * DM + k0;
      bf16x8 b0 = ld8(wrow + 8 * g);
      bf16x8 b1 = ld8(wrow + 32 + 8 * g);
      acc[s] = __builtin_amdgcn_mfma_f32_16x16x32_bf16(a0, b0, acc[s], 0, 0, 0);
      acc[s] = __builtin_amdgcn_mfma_f32_16x16x32_bf16(a1, b1, acc[s], 0, 0, 0);
    }
  }
  if (p != 2) {
    #pragma unroll
    for (int s = 0; s < 4; ++s) {
      float bs = bias[16 * s + c];
      #pragma unroll
      for (int r = 0; r < 4; ++r) {
        int row = row0 + wq * 16 + 4 * g + r;
        out[(size_t)row * DD + 16 * s + c] = f2b(acc[s][r] + bs);
      }
    }
  } else {
    // transpose via x_s bounce -> vpT[b][dv][key], coalesced 16B stores
    __syncthreads();   // all waves done reading x_s from the k-loop
    #pragma unroll
    for (int s = 0; s < 4; ++s) {
      float bs = bias[16 * s + c];
      #pragma unroll
      for (int r = 0; r < 4; ++r)
        x_s[16 * s + c][wq * 16 + 4 * g + r] = f2b(acc[s][r] + bs);
    }
    __syncthreads();
    int d = tid >> 2, q4 = (tid & 3) * 16;
    int bb = row0 >> 11, s0 = row0 & (SS - 1);
    unsigned short* dst = vpT + ((size_t)bb * DD + d) * SS + s0 + q4;
    *(uint4*)dst = *(uint4*)&x_s[d][q4];
    *(uint4*)(dst + 8) = *(uint4*)&x_s[d][q4 + 8];
  }
}

// ------- flash attention: INTERLEAVED k-splits (DRAM-row-friendly) -------
// Split ks owns key chunks {ks*64 + t*kstep : t=0..3}, kstep = nks*64.
// At tile t the 8 co-resident splits read contiguous 2KB of every bias row.
// K/V glds-staged once (source-pre-swizzled, linear LDS); barrier-free loop.
template<bool BYTE>
static __device__ __forceinline__ void attn_body(
    unsigned short* k_sf, unsigned short* v_tf, unsigned short (*p_s)[16][72],
    const unsigned short* __restrict__ qp, const unsigned short* __restrict__ kp,
    const unsigned short* __restrict__ vpT, const float* __restrict__ g_bias,
    const void* __restrict__ mask, float bscale,
    int b, int qw, int wq, int g, int c, int lane, int ks, int kstep,
    float* __restrict__ part_o, float* __restrict__ part_ml) {

  const unsigned short* qrow = qp + (size_t)(b * SS + qw + c) * DD;
  bf16x8 qf0 = ld8(qrow + 8 * g);
  bf16x8 qf1 = ld8(qrow + 32 + 8 * g);
  const size_t rq = (size_t)(b * SS + qw + c) * SS;   // my q-row in bias/mask
  const int kb0 = ks * 64;                             // chunk-t key base = kb0 + t*kstep

  // tile-0 bias/mask issued first (in flight during staging)
  f32x4 bcur[4]; unsigned mcur[4];
  #pragma unroll
  for (int i = 0; i < 4; ++i) {
    const size_t kb = rq + kb0 + 16 * i + 4 * g;
    bcur[i] = *(const f32x4*)(g_bias + kb);
    if (BYTE) {
      mcur[i] = *(const unsigned*)((const unsigned char*)mask + kb);
    } else {
      uint4 mw = *(const uint4*)((const unsigned*)mask + kb);
      mcur[i] = (mw.x ? 1u : 0u) | (mw.y ? 2u : 0u) | (mw.z ? 4u : 0u) | (mw.w ? 8u : 0u);
    }
  }

  {  // ---- async staging: 8 K + 8 V glds per wave, zero VGPR held, one drain
    const unsigned short* kglob = kp + (size_t)b * SS * DD;
    const unsigned short* vglob = vpT + (size_t)b * DD * SS;
    #pragma unroll
    for (int u = 0; u < 8; ++u) {
      int iw = wq * 8 + u;
      {  // K: LDS key-position row = iw*8 + lane/8; granule = (lane%8)^(row&7)
        int row = iw * 8 + (lane >> 3);
        int gk = kb0 + (row >> 6) * kstep + (row & 63);
        int sgr = (lane & 7) ^ (row & 7);
        glds16(kglob + (size_t)gk * DD + sgr * 8, k_sf + iw * 512);
      }
      {  // V: d-row = iw*2 + lane/32; granule covers 8 key-positions
        int row = iw * 2 + (lane >> 5);
        int sgr = (lane & 31) ^ (row & 7);              // XOR stays within chunk
        int gk = kb0 + (sgr >> 3) * kstep + (sgr & 7) * 8;
        glds16(vglob + (size_t)row * SS + gk, v_tf + iw * 512);
      }
    }
  }
  __syncthreads();   // the ONLY barrier (drains glds + bias loads)

  float m_r = -1e30f, l_r = 0.f;
  f32x4 o[4];
  #pragma unroll
  for (int s = 0; s < 4; ++s) o[s] = (f32x4){0.f, 0.f, 0.f, 0.f};

  for (int kt = 0; kt < KLEN; kt += 64) {
    // issue NEXT chunk's bias/mask (stays in flight under this tile's compute)
    f32x4 bnx[4]; unsigned mnx[4];
    if (kt + 64 < KLEN) {
      const int nb = kb0 + ((kt >> 6) + 1) * kstep;
      #pragma unroll
      for (int i = 0; i < 4; ++i) {
        const size_t kb = rq + nb + 16 * i + 4 * g;
        bnx[i] = *(const f32x4*)(g_bias + kb);
        if (BYTE) {
          mnx[i] = *(const unsigned*)((const unsigned char*)mask + kb);
        } else {
          uint4 mw = *(const uint4*)((const unsigned*)mask + kb);
          mnx[i] = (mw.x ? 1u : 0u) | (mw.y ? 2u : 0u) | (mw.z ? 4u : 0u) | (mw.w ? 8u : 0u);
        }
      }
    }
    // swapped QK^T from LDS (swizzled reads)
    f32x4 sa[4];
    #pragma unroll
    for (int i = 0; i < 4; ++i) sa[i] = (f32x4){0.f, 0.f, 0.f, 0.f};
    #pragma unroll
    for (int i = 0; i < 4; ++i) {
      int r = kt + 16 * i + c;
      const unsigned short* krw = k_sf + r * 64;
      bf16x8 a0 = ld8(krw + ((g ^ (r & 7)) << 3));
      bf16x8 a1 = ld8(krw + (((4 + g) ^ (r & 7)) << 3));
      sa[i] = __builtin_amdgcn_mfma_f32_16x16x32_bf16(a0, qf0, sa[i], 0, 0, 0);
      sa[i] = __builtin_amdgcn_mfma_f32_16x16x32_bf16(a1, qf1, sa[i], 0, 0, 0);
    }
    float sc[16];
    #pragma unroll
    for (int i = 0; i < 4; ++i) {
      #pragma unroll
      for (int r = 0; r < 4; ++r) {
        bool msk = BYTE ? (((mcur[i] >> (8 * r)) & 0xFFu) != 0u)
                        : (((mcur[i] >> r) & 1u) != 0u);
        float x = sa[i][r] * 0.125f + bcur[i][r] * bscale;
        sc[4 * i + r] = msk ? -1e30f : x;
      }
    }
    // online softmax: my q-row lives across the 4 g-lanes
    float mx = sc[0];
    #pragma unroll
    for (int i2 = 1; i2 < 16; ++i2) mx = fmaxf(mx, sc[i2]);
    mx = fmaxf(mx, __shfl_xor(mx, 16));
    mx = fmaxf(mx, __shfl_xor(mx, 32));
    float mn = fmaxf(m_r, mx);
    float scl = __expf(m_r - mn);
    float sum = 0.f;
    #pragma unroll
    for (int i2 = 0; i2 < 16; ++i2) {
      sc[i2] = __expf(sc[i2] - mn);        // masked: underflows to 0
      sum += sc[i2];
    }
    sum += __shfl_xor(sum, 16);
    sum += __shfl_xor(sum, 32);
    l_r = l_r * scl + sum;
    m_r = mn;
    // P^T -> wave-private p_s (same-wave ds ordering, no barrier)
    #pragma unroll
    for (int i = 0; i < 4; ++i) {
      uint2 u;
      u.x = (unsigned)f2b(sc[4 * i]) | ((unsigned)f2b(sc[4 * i + 1]) << 16);
      u.y = (unsigned)f2b(sc[4 * i + 2]) | ((unsigned)f2b(sc[4 * i + 3]) << 16);
      *(uint2*)&p_s[wq][c][16 * i + 4 * g] = u;
    }
    // O rows are q=4g+r -> broadcast scl from lane (g'=0, c'=4g+r)
    float scl4[4];
    #pragma unroll
    for (int r = 0; r < 4; ++r) scl4[r] = __shfl(scl, 4 * g + r);
    #pragma unroll
    for (int s2 = 0; s2 < 4; ++s2) {
      #pragma unroll
      for (int r = 0; r < 4; ++r) o[s2][r] *= scl4[r];
    }
    // PV from LDS (swizzled): O[q=4g+r][dv=16s2+c] += P[q][key] * V^T[dv][key]
    bf16x8 pa0 = ld8(&p_s[wq][c][8 * g]);
    bf16x8 pa1 = ld8(&p_s[wq][c][32 + 8 * g]);
    const int gb0 = kt >> 3;
    #pragma unroll
    for (int s2 = 0; s2 < 4; ++s2) {
      int row = 16 * s2 + c;
      const unsigned short* vr = v_tf + row * KLEN;
      bf16x8 v0 = ld8(vr + (((gb0 + g) ^ (row & 7)) << 3));
      bf16x8 v1 = ld8(vr + (((gb0 + 4 + g) ^ (row & 7)) << 3));
      o[s2] = __builtin_amdgcn_mfma_f32_16x16x32_bf16(pa0, v0, o[s2], 0, 0, 0);
      o[s2] = __builtin_amdgcn_mfma_f32_16x16x32_bf16(pa1, v1, o[s2], 0, 0, 0);
    }
    #pragma unroll
    for (int i = 0; i < 4; ++i) { bcur[i] = bnx[i]; mcur[i] = mnx[i]; }
  }
  // epilogue: raw partial (unnormalized O, running m, l) — permutation-invariant
  const size_t gr0 = (size_t)b * SS + qw;
  #pragma unroll
  for (int s2 = 0; s2 < 4; ++s2) {
    #pragma unroll
    for (int r = 0; r < 4; ++r)
      part_o[((size_t)ks * NR + gr0 + 4 * g + r) * DD + 16 * s2 + c] = o[s2][r];
  }
  if (g == 0) {
    size_t row = (size_t)ks * NR + gr0 + c;
    part_ml[row * 2] = m_r;
    part_ml[row * 2 + 1] = l_r;
  }
}

__global__ __launch_bounds__(256, 2) void attn_mfma(
    const unsigned short* __restrict__ qp, const unsigned short* __restrict__ kp,
    const unsigned short* __restrict__ vpT, const float* __restrict__ g_bias,
    const void* __restrict__ mask, const int* __restrict__ viol,
    const float* __restrict__ tau, float* __restrict__ part_o,
    float* __restrict__ part_ml, int nks) {
  __shared__ unsigned short k_sf[KLEN * 64];   // 32 KB, swizzled linear
  __shared__ unsigned short v_tf[64 * KLEN];   // 32 KB, swizzled linear
  __shared__ unsigned short p_s[4][16][72];
  const int b = blockIdx.y;
  const int qb = blockIdx.x / nks;
  const int ks = blockIdx.x - qb * nks;
  const int tid = threadIdx.x;
  const int wq = tid >> 6, lane = tid & 63, g = lane >> 4, c = lane & 15;
  const int qw = qb * 64 + wq * 16;
  const int kstep = nks * 64;
  const bool bytemode = (viol[0] != 0) && (viol[1] != 0) && (viol[2] == 0);
  const float tv = tau[0];
  const float bscale = 1.0f / (2.0f * tv * tv);
  if (bytemode)
    attn_body<true>(k_sf, v_tf, p_s, qp, kp, vpT, g_bias, mask, bscale,
                    b, qw, wq, g, c, lane, ks, kstep, part_o, part_ml);
  else
    attn_body<false>(k_sf, v_tf, p_s, qp, kp, vpT, g_bias, mask, bscale,
                     b, qw, wq, g, c, lane, ks, kstep, part_o, part_ml);
}

// ------- combine partials + output projection via MFMA -------
__global__ __launch_bounds__(256, 4) void fc_mfma(
    const float* __restrict__ part_o, const float* __restrict__ part_ml,
    const unsigned short* __restrict__ WfcT, const float* __restrict__ bfc,
    float* __restrict__ out, int nks) {
  const int row0 = blockIdx.x * 16;
  const int tid = threadIdx.x;
  const int w = tid >> 6, lane = tid & 63, g = lane >> 4, c = lane & 15;
  __shared__ unsigned short a16[16][72];
  {
    int r = tid >> 4, d4 = (tid & 15) * 4;
    size_t grow = (size_t)row0 + r;
    float M = -1e30f;
    for (int i = 0; i < nks; ++i) M = fmaxf(M, part_ml[((size_t)i * NR + grow) * 2]);
    float L = 0.f;
    float4 oa = {0.f, 0.f, 0.f, 0.f};
    for (int i = 0; i < nks; ++i) {
      float mi = part_ml[((size_t)i * NR + grow) * 2];
      float li = part_ml[((size_t)i * NR + grow) * 2 + 1];
      float wgt = __expf(mi - M);
      L += li * wgt;
      float4 ov = *(const float4*)&part_o[((size_t)i * NR + grow) * DD + d4];
      oa.x += wgt * ov.x; oa.y += wgt * ov.y; oa.z += wgt * ov.z; oa.w += wgt * ov.w;
    }
    float inv = (L > 0.f) ? 1.0f / L : 0.f;
    a16[r][d4 + 0] = f2b(oa.x * inv);
    a16[r][d4 + 1] = f2b(oa.y * inv);
    a16[r][d4 + 2] = f2b(oa.z * inv);
    a16[r][d4 + 3] = f2b(oa.w * inv);
  }
  __syncthreads();
  bf16x8 a0 = ld8(&a16[c][8 * g]);
  bf16x8 a1 = ld8(&a16[c][32 + 8 * g]);
  f32x4 acc[8];
  #pragma unroll
  for (int s = 0; s < 8; ++s) acc[s] = (f32x4){0.f, 0.f, 0.f, 0.f};
  #pragma unroll
  for (int s = 0; s < 8; ++s) {
    const unsigned short* bp = WfcT + (size_t)(128 * w + 16 * s + c) * DD;
    bf16x8 b0 = ld8(bp + 8 * g);
    bf16x8 b1 = ld8(bp + 32 + 8 * g);
    acc[s] = __builtin_amdgcn_mfma_f32_16x16x32_bf16(a0, b0, acc[s], 0, 0, 0);
    acc[s] = __builtin_amdgcn_mfma_f32_16x16x32_bf16(a1, b1, acc[s], 0, 0, 0);
  }
  #pragma unroll
  for (int s = 0; s < 8; ++s) {
    int col = 128 * w + 16 * s + c;
    float bb = bfc[col];
    #pragma unroll
    for (int rr = 0; rr < 4; ++rr)
      out[(size_t)(row0 + 4 * g + rr) * DM + col] = acc[s][rr] + bb;
  }
}

extern "C" void kernel_launch(void* const* d_in, const int* in_sizes, int n_in,
                              void* d_out, int out_size, void* d_ws, size_t ws_size,
                              hipStream_t stream) {
  const float* q    = (const float*)d_in[0];
  const float* k    = (const float*)d_in[1];
  const float* v    = (const float*)d_in[2];
  const float* gb   = (const float*)d_in[3];
  const void*  mask = d_in[4];
  const float* Wq   = (const float*)d_in[5];
  const float* bq   = (const float*)d_in[6];
  const float* Wk   = (const float*)d_in[7];
  const float* bk   = (const float*)d_in[8];
  const float* Wv   = (const float*)d_in[9];
  const float* bv   = (const float*)d_in[10];
  const float* Wfc  = (const float*)d_in[11];
  const float* bfc  = (const float*)d_in[12];
  const float* tau  = (const float*)d_in[13];
  float* out = (float*)d_out;

  char* ws = (char*)d_ws;
  int* viol = (int*)ws;                                       // 3 ints
  int* part = (int*)(ws + 256);                               // 64 blocks * 4 ints
  unsigned short* Wt   = (unsigned short*)(ws + 8192);        // 196608 B
  unsigned short* WfcT = (unsigned short*)(ws + 8192 + 196608);  // 65536 B
  unsigned short* qp  = (unsigned short*)(ws + 8192 + 196608 + 65536);
  unsigned short* kp  = qp + (size_t)NR * DD;
  unsigned short* vpT = kp + (size_t)NR * DD;                 // [NB][DD][SS]
  char* pbase = (char*)(vpT + (size_t)NB * DD * SS);
  size_t used = (size_t)(pbase - ws);
  size_t per = (size_t)NR * DD * 4 + (size_t)NR * 2 * 4;      // part_o + part_ml per split
  int nks = (ws_size >= used + 8 * per) ? 8 : 1;              // KLEN=256 requires 8
  float* part_o = (float*)pbase;
  float* part_ml = part_o + (size_t)nks * NR * DD;

  detect_mask<<<64, 256, 0, stream>>>((const unsigned*)mask, in_sizes[4] / 4, part);
  reduce_flags<<<1, 256, 0, stream>>>(part, 64, viol);
  transpose_w<<<dim3(8, 3), 256, 0, stream>>>(Wq, Wk, Wv, Wt);
  transpose_wfc<<<8, 256, 0, stream>>>(Wfc, WfcT);
  proj_mfma<<<dim3(NR / 64, 3), 256, 0, stream>>>(q, k, v, Wt, bq, bk, bv, qp, kp, vpT);
  attn_mfma<<<dim3((SS / 64) * nks, NB), 256, 0, stream>>>(
      qp, kp, vpT, gb, mask, viol, tau, part_o, part_ml, nks);
  fc_mfma<<<NR / 16, 256, 0, stream>>>(part_o, part_ml, WfcT, bfc, out, nks);
}

// Round 13
// 78.927 us; speedup vs baseline: 1.0383x; 1.0383x over previous
//
#include <hip/hip_runtime.h>

#define NB 4
#define SS 2048
#define DM 512
#define DD 64
#define NR (NB*SS)
#define PH 128          // keys per phase
#define NKS 8           // k-splits (klen = 256 = 2 phases)

typedef __attribute__((ext_vector_type(8))) short bf16x8;
typedef __attribute__((ext_vector_type(4))) float f32x4;

static __device__ __forceinline__ unsigned short f2b(float f) {
  union { float f; unsigned u; } x; x.f = f;
  unsigned r = x.u + 0x7FFFu + ((x.u >> 16) & 1u);
  return (unsigned short)(r >> 16);
}
static __device__ __forceinline__ float b2f(unsigned short h) {
  union { unsigned u; float f; } x; x.u = ((unsigned)h) << 16; return x.f;
}
static __device__ __forceinline__ bf16x8 ld8(const unsigned short* p) {
  union { uint4 u; bf16x8 v; } x; x.u = *(const uint4*)p; return x.v;
}
static __device__ __forceinline__ void glds16(const void* g, void* l) {
  auto gp = (const __attribute__((address_space(1))) unsigned*)((__UINTPTR_TYPE__)g);
  auto lp = (__attribute__((address_space(3))) unsigned*)((__UINTPTR_TYPE__)l);
  __builtin_amdgcn_global_load_lds(gp, lp, 16, 0, 0);
}

// ------- mask dtype detection: stride-64 sampled scan, per-block flags -------
__global__ __launch_bounds__(256) void detect_mask(const unsigned* __restrict__ mw,
                                                   int nwords, int* __restrict__ part) {
  const int gid = blockIdx.x * 256 + threadIdx.x;
  const int nthr = gridDim.x * 256;
  int vi = 0, vf = 0, vu = 0;
  for (long i = (long)gid * 64; i < nwords; i += (long)nthr * 64) {
    unsigned w = mw[i];
    vi |= (w > 1u);
    vf |= ((w != 0u) & (w != 0x3F800000u));
    vu |= ((w & 0xFEFEFEFEu) != 0u);
  }
  __shared__ int sh[3];
  if (threadIdx.x < 3) sh[threadIdx.x] = 0;
  __syncthreads();
  int lane = threadIdx.x & 63;
  unsigned long long b;
  b = __ballot(vi); if (lane == 0 && b) sh[0] = 1;   // benign same-value races
  b = __ballot(vf); if (lane == 0 && b) sh[1] = 1;
  b = __ballot(vu); if (lane == 0 && b) sh[2] = 1;
  __syncthreads();
  if (threadIdx.x < 3) part[blockIdx.x * 4 + threadIdx.x] = sh[threadIdx.x];
}

// ------- prep: Wq/Wk/Wv transpose (blocks 0-23) + Wfc transpose (24-31) -------
__global__ __launch_bounds__(256) void prep(
    const float* __restrict__ Wq, const float* __restrict__ Wk, const float* __restrict__ Wv,
    unsigned short* __restrict__ Wt,
    const float* __restrict__ Wfc, unsigned short* __restrict__ WfcT) {
  const int bid = blockIdx.x;
  const int t = threadIdx.x;
  if (bid < 24) {
    const int p = bid >> 3;
    const float* W = (p == 0) ? Wq : ((p == 1) ? Wk : Wv);
    const int k0 = (bid & 7) * 64;
    const int n0 = (t & 15) * 4;
    #pragma unroll
    for (int p2 = 0; p2 < 4; ++p2) {
      int k = k0 + (t >> 4) + 16 * p2;
      float4 w = *(const float4*)(W + (size_t)k * DD + n0);
      Wt[(size_t)(p * DD + n0 + 0) * DM + k] = f2b(w.x);
      Wt[(size_t)(p * DD + n0 + 1) * DM + k] = f2b(w.y);
      Wt[(size_t)(p * DD + n0 + 2) * DM + k] = f2b(w.z);
      Wt[(size_t)(p * DD + n0 + 3) * DM + k] = f2b(w.w);
    }
  } else {
    const int n0 = (bid - 24) * 64;
    __shared__ unsigned short wt[64][68];
    {
      int k = t >> 2, j = (t & 3) * 16;
      #pragma unroll
      for (int u = 0; u < 4; ++u) {
        float4 w = *(const float4*)(Wfc + (size_t)k * DM + n0 + j + 4 * u);
        wt[k][j + 4 * u + 0] = f2b(w.x);
        wt[k][j + 4 * u + 1] = f2b(w.y);
        wt[k][j + 4 * u + 2] = f2b(w.z);
        wt[k][j + 4 * u + 3] = f2b(w.w);
      }
    }
    __syncthreads();
    {
      int n = t >> 2, kq = (t & 3) * 16;
      unsigned short tmp[16];
      #pragma unroll
      for (int u = 0; u < 16; ++u) tmp[u] = wt[kq + u][n];
      *(uint4*)(WfcT + (size_t)(n0 + n) * DD + kq) = *(uint4*)&tmp[0];
      *(uint4*)(WfcT + (size_t)(n0 + n) * DD + kq + 8) = *(uint4*)&tmp[8];
    }
  }
}

// ------- projections via MFMA; V output written TRANSPOSED (vpT[b][dv][key]) -------
__global__ __launch_bounds__(256, 4) void proj_mfma(
    const float* __restrict__ q, const float* __restrict__ k, const float* __restrict__ v,
    const unsigned short* __restrict__ Wt,
    const float* __restrict__ bq, const float* __restrict__ bk, const float* __restrict__ bv,
    unsigned short* __restrict__ qp, unsigned short* __restrict__ kp,
    unsigned short* __restrict__ vpT) {
  const int p = blockIdx.y;
  const float* X = (p == 0) ? q : ((p == 1) ? k : v);
  const float* bias = (p == 0) ? bq : ((p == 1) ? bk : bv);
  unsigned short* out = (p == 0) ? qp : kp;   // p==2 goes through vpT path
  const int row0 = blockIdx.x * 64;
  const int tid = threadIdx.x;
  const int wq = tid >> 6, lane = tid & 63, g = lane >> 4, c = lane & 15;
  __shared__ unsigned short x_s[64][72];
  f32x4 acc[4];
  #pragma unroll
  for (int s = 0; s < 4; ++s) acc[s] = (f32x4){0.f, 0.f, 0.f, 0.f};
  const unsigned short* wbase = Wt + (size_t)p * DD * DM;

  for (int k0 = 0; k0 < DM; k0 += 64) {
    __syncthreads();
    #pragma unroll
    for (int pp = 0; pp < 4; ++pp) {
      int f = tid + 256 * pp;
      int r = f >> 4, c4 = (f & 15) << 2;
      float4 xv = *(const float4*)(X + (size_t)(row0 + r) * DM + k0 + c4);
      uint2 u;
      u.x = (unsigned)f2b(xv.x) | ((unsigned)f2b(xv.y) << 16);
      u.y = (unsigned)f2b(xv.z) | ((unsigned)f2b(xv.w) << 16);
      *(uint2*)&x_s[r][c4] = u;
    }
    __syncthreads();
    const unsigned short* xrow = &x_s[wq * 16 + c][0];
    bf16x8 a0 = ld8(xrow + 8 * g);
    bf16x8 a1 = ld8(xrow + 32 + 8 * g);
    #pragma unroll
    for (int s = 0; s < 4; ++s) {
      const unsigned short* wrow = wbase + (size_t)(16 * s + c) * DM + k0;
      bf16x8 b0 = ld8(wrow + 8 * g);
      bf16x8 b1 = ld8(wrow + 32 + 8 * g);
      acc[s] = __builtin_amdgcn_mfma_f32_16x16x32_bf16(a0, b0, acc[s], 0, 0, 0);
      acc[s] = __builtin_amdgcn_mfma_f32_16x16x32_bf16(a1, b1, acc[s], 0, 0, 0);
    }
  }
  if (p != 2) {
    #pragma unroll
    for (int s = 0; s < 4; ++s) {
      float bs = bias[16 * s + c];
      #pragma unroll
      for (int r = 0; r < 4; ++r) {
        int row = row0 + wq * 16 + 4 * g + r;
        out[(size_t)row * DD + 16 * s + c] = f2b(acc[s][r] + bs);
      }
    }
  } else {
    __syncthreads();   // all waves done reading x_s from the k-loop
    #pragma unroll
    for (int s = 0; s < 4; ++s) {
      float bs = bias[16 * s + c];
      #pragma unroll
      for (int r = 0; r < 4; ++r)
        x_s[16 * s + c][wq * 16 + 4 * g + r] = f2b(acc[s][r] + bs);
    }
    __syncthreads();
    int d = tid >> 2, q4 = (tid & 3) * 16;
    int bb = row0 >> 11, s0 = row0 & (SS - 1);
    unsigned short* dst = vpT + ((size_t)bb * DD + d) * SS + s0 + q4;
    *(uint4*)dst = *(uint4*)&x_s[d][q4];
    *(uint4*)(dst + 8) = *(uint4*)&x_s[d][q4 + 8];
  }
}

// ------- flash attention: 2 phases x 128 keys; bias+mask staged to LDS with
// CONTIGUOUS per-instruction loads (mechanism under test, grid FIXED) -------
template<bool BYTE>
static __device__ __forceinline__ void attn_body(
    unsigned short* k_sf, unsigned short* v_tf, unsigned short* bias_s,
    unsigned short (*p_s)[16][72],
    const unsigned short* __restrict__ qp, const unsigned short* __restrict__ kp,
    const unsigned short* __restrict__ vpT, const float* __restrict__ g_bias,
    const void* __restrict__ mask, float bscale,
    int b, int qb, int wq, int g, int c, int lane, int kbeg,
    int ks, float* __restrict__ part_o, float* __restrict__ part_ml) {

  const int qw = qb * 64 + wq * 16;
  const unsigned short* qrow = qp + (size_t)(b * SS + qw + c) * DD;
  bf16x8 qf0 = ld8(qrow + 8 * g);
  bf16x8 qf1 = ld8(qrow + 32 + 8 * g);
  const unsigned short* kglob = kp + (size_t)b * SS * DD;
  const unsigned short* vglob = vpT + (size_t)b * DD * SS;

  float m_r = -1e30f, l_r = 0.f;
  f32x4 o[4];
  #pragma unroll
  for (int s = 0; s < 4; ++s) o[s] = (f32x4){0.f, 0.f, 0.f, 0.f};

  #pragma unroll 1
  for (int p = 0; p < 2; ++p) {
    const int kb = kbeg + p * PH;
    if (p) __syncthreads();                 // protect LDS before overwrite

    // ---- bias+mask: contiguous per-instruction loads, fold mask, -> LDS bf16
    // instr u: lane covers row_l = wq*16 + u*2 + lane/32, keys (lane%32)*4..+3
    {
      const int rl = wq * 16 + (lane >> 5);
      const int key4 = (lane & 31) * 4;
      #pragma unroll
      for (int u = 0; u < 8; ++u) {
        const int row_l = rl + u * 2;
        const size_t idx = (size_t)(b * SS + qb * 64 + row_l) * SS + kb + key4;
        f32x4 bv = *(const f32x4*)(g_bias + idx);
        unsigned short h[4];
        if (BYTE) {
          unsigned m = *(const unsigned*)((const unsigned char*)mask + idx);
          #pragma unroll
          for (int e = 0; e < 4; ++e)
            h[e] = ((m >> (8 * e)) & 0xFFu) ? (unsigned short)0xFF80u
                                            : f2b(bv[e] * bscale);
        } else {
          uint4 m = *(const uint4*)((const unsigned*)mask + idx);
          unsigned mw[4] = {m.x, m.y, m.z, m.w};
          #pragma unroll
          for (int e = 0; e < 4; ++e)
            h[e] = mw[e] ? (unsigned short)0xFF80u : f2b(bv[e] * bscale);
        }
        uint2 w;
        w.x = (unsigned)h[0] | ((unsigned)h[1] << 16);
        w.y = (unsigned)h[2] | ((unsigned)h[3] << 16);
        *(uint2*)&bias_s[row_l * 140 + key4] = w;
      }
    }
    // ---- K/V async staging (glds, source-pre-swizzled, linear LDS)
    #pragma unroll
    for (int u = 0; u < 4; ++u) {
      int iw = wq * 4 + u;
      {  // K: 8 rows x 64el per instr
        int row = iw * 8 + (lane >> 3);
        int sgr = (lane & 7) ^ (row & 7);
        glds16(kglob + (size_t)(kb + row) * DD + sgr * 8, k_sf + iw * 512);
      }
      {  // V^T: 4 rows x 128el per instr
        int row = iw * 4 + (lane >> 4);
        int sgr = (lane & 15) ^ (row & 7);
        glds16(vglob + (size_t)row * SS + kb + sgr * 8, v_tf + iw * 512);
      }
    }
    __syncthreads();                        // staging complete

    // ---- 2 tiles of 64 keys, zero global loads
    #pragma unroll 1
    for (int kt = 0; kt < PH; kt += 64) {
      f32x4 sa[4];
      #pragma unroll
      for (int i = 0; i < 4; ++i) sa[i] = (f32x4){0.f, 0.f, 0.f, 0.f};
      #pragma unroll
      for (int i = 0; i < 4; ++i) {
        int r = kt + 16 * i + c;
        const unsigned short* krw = k_sf + r * 64;
        bf16x8 a0 = ld8(krw + ((g ^ (r & 7)) << 3));
        bf16x8 a1 = ld8(krw + (((4 + g) ^ (r & 7)) << 3));
        sa[i] = __builtin_amdgcn_mfma_f32_16x16x32_bf16(a0, qf0, sa[i], 0, 0, 0);
        sa[i] = __builtin_amdgcn_mfma_f32_16x16x32_bf16(a1, qf1, sa[i], 0, 0, 0);
      }
      // scores: bias (pre-scaled, mask folded to -inf) from LDS
      float sc[16];
      const int brow = (wq * 16 + c) * 140;
      #pragma unroll
      for (int i = 0; i < 4; ++i) {
        uint2 bw = *(const uint2*)&bias_s[brow + kt + 16 * i + 4 * g];
        sc[4 * i + 0] = sa[i][0] * 0.125f + b2f((unsigned short)(bw.x & 0xFFFFu));
        sc[4 * i + 1] = sa[i][1] * 0.125f + b2f((unsigned short)(bw.x >> 16));
        sc[4 * i + 2] = sa[i][2] * 0.125f + b2f((unsigned short)(bw.y & 0xFFFFu));
        sc[4 * i + 3] = sa[i][3] * 0.125f + b2f((unsigned short)(bw.y >> 16));
      }
      // online softmax: my q-row lives across the 4 g-lanes
      float mx = sc[0];
      #pragma unroll
      for (int i2 = 1; i2 < 16; ++i2) mx = fmaxf(mx, sc[i2]);
      mx = fmaxf(mx, __shfl_xor(mx, 16));
      mx = fmaxf(mx, __shfl_xor(mx, 32));
      float mn = fmaxf(m_r, mx);
      float scl = __expf(m_r - mn);
      float sum = 0.f;
      #pragma unroll
      for (int i2 = 0; i2 < 16; ++i2) {
        sc[i2] = __expf(sc[i2] - mn);       // masked (-inf): exp -> 0
        sum += sc[i2];
      }
      sum += __shfl_xor(sum, 16);
      sum += __shfl_xor(sum, 32);
      l_r = l_r * scl + sum;
      m_r = mn;
      #pragma unroll
      for (int i = 0; i < 4; ++i) {
        uint2 u;
        u.x = (unsigned)f2b(sc[4 * i]) | ((unsigned)f2b(sc[4 * i + 1]) << 16);
        u.y = (unsigned)f2b(sc[4 * i + 2]) | ((unsigned)f2b(sc[4 * i + 3]) << 16);
        *(uint2*)&p_s[wq][c][16 * i + 4 * g] = u;
      }
      float scl4[4];
      #pragma unroll
      for (int r = 0; r < 4; ++r) scl4[r] = __shfl(scl, 4 * g + r);
      #pragma unroll
      for (int s2 = 0; s2 < 4; ++s2) {
        #pragma unroll
        for (int r = 0; r < 4; ++r) o[s2][r] *= scl4[r];
      }
      // PV from LDS
      bf16x8 pa0 = ld8(&p_s[wq][c][8 * g]);
      bf16x8 pa1 = ld8(&p_s[wq][c][32 + 8 * g]);
      const int gb0 = kt >> 3;
      #pragma unroll
      for (int s2 = 0; s2 < 4; ++s2) {
        int row = 16 * s2 + c;
        const unsigned short* vr = v_tf + row * PH;
        bf16x8 v0 = ld8(vr + (((gb0 + g) ^ (row & 7)) << 3));
        bf16x8 v1 = ld8(vr + (((gb0 + 4 + g) ^ (row & 7)) << 3));
        o[s2] = __builtin_amdgcn_mfma_f32_16x16x32_bf16(pa0, v0, o[s2], 0, 0, 0);
        o[s2] = __builtin_amdgcn_mfma_f32_16x16x32_bf16(pa1, v1, o[s2], 0, 0, 0);
      }
    }
  }
  // epilogue: raw partial (unnormalized O, running m, l)
  const size_t gr0 = (size_t)b * SS + qw;
  #pragma unroll
  for (int s2 = 0; s2 < 4; ++s2) {
    #pragma unroll
    for (int r = 0; r < 4; ++r)
      part_o[((size_t)ks * NR + gr0 + 4 * g + r) * DD + 16 * s2 + c] = o[s2][r];
  }
  if (g == 0) {
    size_t row = (size_t)ks * NR + gr0 + c;
    part_ml[row * 2] = m_r;
    part_ml[row * 2 + 1] = l_r;
  }
}

__global__ __launch_bounds__(256, 2) void attn_mfma(
    const unsigned short* __restrict__ qp, const unsigned short* __restrict__ kp,
    const unsigned short* __restrict__ vpT, const float* __restrict__ g_bias,
    const void* __restrict__ mask, const int* __restrict__ part,
    const float* __restrict__ tau, float* __restrict__ part_o,
    float* __restrict__ part_ml) {
  __shared__ unsigned short k_sf[PH * 64];      // 16 KB
  __shared__ unsigned short v_tf[64 * PH];      // 16 KB
  __shared__ unsigned short bias_s[64 * 140];   // 17.9 KB (pad 140)
  __shared__ unsigned short p_s[4][16][72];     // 9.2 KB
  __shared__ int shf[3];
  const int tid = threadIdx.x;
  // per-block flag reduce (replaces reduce_flags kernel)
  if (tid < 64) {
    int a0 = part[tid * 4], a1 = part[tid * 4 + 1], a2 = part[tid * 4 + 2];
    unsigned long long b0 = __ballot(a0 != 0);
    unsigned long long b1 = __ballot(a1 != 0);
    unsigned long long b2 = __ballot(a2 != 0);
    if (tid == 0) {
      shf[0] = b0 ? 1 : 0; shf[1] = b1 ? 1 : 0; shf[2] = b2 ? 1 : 0;
    }
  }
  __syncthreads();
  const bool bytemode = shf[0] && shf[1] && !shf[2];
  const int b = blockIdx.y;
  const int qb = blockIdx.x >> 3;          // 0..31  (grid x = 256)
  const int ks = blockIdx.x & 7;           // 0..7
  const int wq = tid >> 6, lane = tid & 63, g = lane >> 4, c = lane & 15;
  const int kbeg = ks * (SS / NKS);
  const float tv = tau[0];
  const float bscale = 1.0f / (2.0f * tv * tv);
  if (bytemode)
    attn_body<true>(k_sf, v_tf, bias_s, p_s, qp, kp, vpT, g_bias, mask, bscale,
                    b, qb, wq, g, c, lane, kbeg, ks, part_o, part_ml);
  else
    attn_body<false>(k_sf, v_tf, bias_s, p_s, qp, kp, vpT, g_bias, mask, bscale,
                     b, qb, wq, g, c, lane, kbeg, ks, part_o, part_ml);
}

// ------- combine partials + output projection via MFMA -------
__global__ __launch_bounds__(256, 4) void fc_mfma(
    const float* __restrict__ part_o, const float* __restrict__ part_ml,
    const unsigned short* __restrict__ WfcT, const float* __restrict__ bfc,
    float* __restrict__ out, int nks) {
  const int row0 = blockIdx.x * 16;
  const int tid = threadIdx.x;
  const int w = tid >> 6, lane = tid & 63, g = lane >> 4, c = lane & 15;
  __shared__ unsigned short a16[16][72];
  {
    int r = tid >> 4, d4 = (tid & 15) * 4;
    size_t grow = (size_t)row0 + r;
    float M = -1e30f;
    for (int i = 0; i < nks; ++i) M = fmaxf(M, part_ml[((size_t)i * NR + grow) * 2]);
    float L = 0.f;
    float4 oa = {0.f, 0.f, 0.f, 0.f};
    for (int i = 0; i < nks; ++i) {
      float mi = part_ml[((size_t)i * NR + grow) * 2];
      float li = part_ml[((size_t)i * NR + grow) * 2 + 1];
      float wgt = __expf(mi - M);
      L += li * wgt;
      float4 ov = *(const float4*)&part_o[((size_t)i * NR + grow) * DD + d4];
      oa.x += wgt * ov.x; oa.y += wgt * ov.y; oa.z += wgt * ov.z; oa.w += wgt * ov.w;
    }
    float inv = (L > 0.f) ? 1.0f / L : 0.f;
    a16[r][d4 + 0] = f2b(oa.x * inv);
    a16[r][d4 + 1] = f2b(oa.y * inv);
    a16[r][d4 + 2] = f2b(oa.z * inv);
    a16[r][d4 + 3] = f2b(oa.w * inv);
  }
  __syncthreads();
  bf16x8 a0 = ld8(&a16[c][8 * g]);
  bf16x8 a1 = ld8(&a16[c][32 + 8 * g]);
  f32x4 acc[8];
  #pragma unroll
  for (int s = 0; s < 8; ++s) acc[s] = (f32x4){0.f, 0.f, 0.f, 0.f};
  #pragma unroll
  for (int s = 0; s < 8; ++s) {
    const unsigned short* bp = WfcT + (size_t)(128 * w + 16 * s + c) * DD;
    bf16x8 b0 = ld8(bp + 8 * g);
    bf16x8 b1 = ld8(bp + 32 + 8 * g);
    acc[s] = __builtin_amdgcn_mfma_f32_16x16x32_bf16(a0, b0, acc[s], 0, 0, 0);
    acc[s] = __builtin_amdgcn_mfma_f32_16x16x32_bf16(a1, b1, acc[s], 0, 0, 0);
  }
  #pragma unroll
  for (int s = 0; s < 8; ++s) {
    int col = 128 * w + 16 * s + c;
    float bb = bfc[col];
    #pragma unroll
    for (int rr = 0; rr < 4; ++rr)
      out[(size_t)(row0 + 4 * g + rr) * DM + col] = acc[s][rr] + bb;
  }
}

extern "C" void kernel_launch(void* const* d_in, const int* in_sizes, int n_in,
                              void* d_out, int out_size, void* d_ws, size_t ws_size,
                              hipStream_t stream) {
  const float* q    = (const float*)d_in[0];
  const float* k    = (const float*)d_in[1];
  const float* v    = (const float*)d_in[2];
  const float* gb   = (const float*)d_in[3];
  const void*  mask = d_in[4];
  const float* Wq   = (const float*)d_in[5];
  const float* bq   = (const float*)d_in[6];
  const float* Wk   = (const float*)d_in[7];
  const float* bk   = (const float*)d_in[8];
  const float* Wv   = (const float*)d_in[9];
  const float* bv   = (const float*)d_in[10];
  const float* Wfc  = (const float*)d_in[11];
  const float* bfc  = (const float*)d_in[12];
  const float* tau  = (const float*)d_in[13];
  float* out = (float*)d_out;

  char* ws = (char*)d_ws;
  int* part = (int*)(ws + 256);                               // 64 blocks * 4 ints
  unsigned short* Wt   = (unsigned short*)(ws + 8192);        // 196608 B
  unsigned short* WfcT = (unsigned short*)(ws + 8192 + 196608);  // 65536 B
  unsigned short* qp  = (unsigned short*)(ws + 8192 + 196608 + 65536);
  unsigned short* kp  = qp + (size_t)NR * DD;
  unsigned short* vpT = kp + (size_t)NR * DD;                 // [NB][DD][SS]
  float* part_o = (float*)(vpT + (size_t)NB * DD * SS);
  float* part_ml = part_o + (size_t)NKS * NR * DD;

  detect_mask<<<64, 256, 0, stream>>>((const unsigned*)mask, in_sizes[4] / 4, part);
  prep<<<32, 256, 0, stream>>>(Wq, Wk, Wv, Wt, Wfc, WfcT);
  proj_mfma<<<dim3(NR / 64, 3), 256, 0, stream>>>(q, k, v, Wt, bq, bk, bv, qp, kp, vpT);
  attn_mfma<<<dim3((SS / 64) * NKS, NB), 256, 0, stream>>>(
      qp, kp, vpT, gb, mask, part, tau, part_o, part_ml);
  fc_mfma<<<NR / 16, 256, 0, stream>>>(part_o, part_ml, WfcT, bfc, out, NKS);
}